// Round 16
// baseline (201.842 us; speedup 1.0000x reference)
//
#include <hip/hip_runtime.h>
#include <cmath>

typedef _Float16 half8 __attribute__((ext_vector_type(8)));
typedef float f32x4 __attribute__((ext_vector_type(4)));

#define GLD_LDS16(gptr, lptr)                                                  \
  __builtin_amdgcn_global_load_lds(                                            \
      (const __attribute__((address_space(1))) void*)(gptr),                   \
      (__attribute__((address_space(3))) void*)(lptr), 16, 0, 0)

#define MEMFENCE asm volatile("" ::: "memory")

// ---------------- merged f32 -> f16 conversion (one dispatch) ---------------
__global__ void cvt_all(const float* __restrict__ s0, const float* __restrict__ s1,
                        const float* __restrict__ s2, const float* __restrict__ s3,
                        _Float16* __restrict__ d0, _Float16* __restrict__ d1,
                        _Float16* __restrict__ d2, _Float16* __restrict__ d3,
                        long nb0, long nb1, long nb2) {
  long b = blockIdx.x;
  const float* s;
  _Float16* d;
  if (b < nb0) {
    s = s0; d = d0;
  } else if (b < nb0 + nb1) {
    s = s1; d = d1; b -= nb0;
  } else if (b < nb0 + nb1 + nb2) {
    s = s2; d = d2; b -= nb0 + nb1;
  } else {
    s = s3; d = d3; b -= nb0 + nb1 + nb2;
  }
  long i = b * 2048 + (long)threadIdx.x * 8;
  const float4* p = (const float4*)(s + i);
  float4 a = p[0];
  float4 c = p[1];
  half8 h = {(_Float16)a.x, (_Float16)a.y, (_Float16)a.z, (_Float16)a.w,
             (_Float16)c.x, (_Float16)c.y, (_Float16)c.z, (_Float16)c.w};
  *(half8*)(d + i) = h;
}

// ============ wave-specialized GEMM, BIG consumer tiles (128x64) ============
// C[m,n] = sum_k A[m,k]*B[n,k].  BM=256, BN=128, BK=64.
// 512 threads = 4 CONSUMER waves (2M x 2N, each owns a 128x64 output tile)
//             + 4 PRODUCER waves (staging only; identical to r15's producers).
// WHY: with 8 consumers x 64x64, block-wide LDS reads are 128 KB/K-tile
// (A read 2x, B read 4x) = 1536 cy > MFMA 1242 cy -> LDS pipe binds and the
// measured 3230 cy/K-tile = reads+writes+MFMA serial. 4 consumers x 128x64
// cut reads to 96 KB (~1150 cy) < MFMA -> matrix pipe becomes top pipe.
// Per consumer wave per K-tile: 24 ds_read_b128 -> 64 MFMA (setprio) ->
// lgkmcnt(0) [WAR] -> s_barrier.  Producer: 12 gld_lds (tile t+2) ->
// vmcnt(12) [t+1 landed, t+2 in flight] -> s_barrier.  Triple buffer,
// distance-2. T2 XOR swizzle via producer source address (layout = r7/r15).
// Grid: 256 blocks = 16x16 tiles; 2-D XCD rects (4 rows x 8 cols of tiles).
// EPI: 0 = acc+bias -> f16 ; 1 = 0.5*tanh(acc+bias) -> f16
template <int EPI>
__global__ __launch_bounds__(512, 2) void gemmw4(
    const _Float16* __restrict__ A, const _Float16* __restrict__ Bm,
    const float* __restrict__ bias, void* __restrict__ Cout, int N, int K) {
  __shared__ _Float16 As[3][256 * 64];
  __shared__ _Float16 Bs[3][128 * 64];

  const int tid = threadIdx.x;
  const int lane = tid & 63;
  const int wave = tid >> 6;

  const int bid = blockIdx.x;
  const int xcd = bid & 7;
  const int idx = bid >> 3;
  const int brow = ((xcd >> 1) * 4 + (idx & 3)) * 256;
  const int bcol = ((xcd & 1) * 8 + (idx >> 2)) * 128;

  const int nt = K >> 6;

  _Float16* sa0 = As[0]; _Float16* sa1 = As[1]; _Float16* sa2 = As[2];
  _Float16* sb0 = Bs[0]; _Float16* sb1 = Bs[1]; _Float16* sb2 = Bs[2];

  if (wave < 4) {
    // =========================== CONSUMER (128x64) ===========================
    const int wr = (wave >> 1) * 128;  // M-half
    const int wc = (wave & 1) * 64;    // N-half

    const int frow = lane & 15;
    const int hi = lane >> 4;
    const int xr = lane & 7;

    int aoff[8], boff[4];
#pragma unroll
    for (int m = 0; m < 8; m++) aoff[m] = (wr + m * 16 + frow) * 64;
#pragma unroll
    for (int n = 0; n < 4; n++) boff[n] = (wc + n * 16 + frow) * 64;
    const int ch0 = (hi ^ xr) * 8;
    const int ch1 = ((4 + hi) ^ xr) * 8;

    f32x4 acc[8][4];
#pragma unroll
    for (int m = 0; m < 8; m++)
#pragma unroll
      for (int n = 0; n < 4; n++) acc[m][n] = f32x4{0.f, 0.f, 0.f, 0.f};

    __builtin_amdgcn_s_barrier();  // tile 0 published by producers
    MEMFENCE;

    for (int t = 0; t < nt; ++t) {
      half8 a0[8], a1[8], b0[4], b1[4];
#pragma unroll
      for (int m = 0; m < 8; m++) a0[m] = *(const half8*)(sa0 + aoff[m] + ch0);
#pragma unroll
      for (int n = 0; n < 4; n++) b0[n] = *(const half8*)(sb0 + boff[n] + ch0);
#pragma unroll
      for (int m = 0; m < 8; m++) a1[m] = *(const half8*)(sa0 + aoff[m] + ch1);
#pragma unroll
      for (int n = 0; n < 4; n++) b1[n] = *(const half8*)(sb0 + boff[n] + ch1);

      __builtin_amdgcn_s_setprio(1);
#pragma unroll
      for (int m = 0; m < 8; m++)
#pragma unroll
        for (int n = 0; n < 4; n++)
          acc[m][n] = __builtin_amdgcn_mfma_f32_16x16x32_f16(a0[m], b0[n],
                                                             acc[m][n], 0, 0, 0);
#pragma unroll
      for (int m = 0; m < 8; m++)
#pragma unroll
        for (int n = 0; n < 4; n++)
          acc[m][n] = __builtin_amdgcn_mfma_f32_16x16x32_f16(a1[m], b1[n],
                                                             acc[m][n], 0, 0, 0);
      __builtin_amdgcn_s_setprio(0);

      asm volatile("s_waitcnt lgkmcnt(0)" ::: "memory");  // reads drained (WAR)
      __builtin_amdgcn_s_barrier();
      MEMFENCE;

      _Float16* ta = sa0; sa0 = sa1; sa1 = sa2; sa2 = ta;
      _Float16* tb = sb0; sb0 = sb1; sb1 = sb2; sb2 = tb;
    }

    // epilogue: C/D layout col = lane&15, row = (lane>>4)*4 + reg
    const int r0 = hi * 4;
    const int c0 = frow;
#pragma unroll
    for (int n = 0; n < 4; n++) {
      const int col = bcol + wc + n * 16 + c0;
      const float bv = bias[col];
#pragma unroll
      for (int m = 0; m < 8; m++) {
#pragma unroll
        for (int r = 0; r < 4; r++) {
          const int row = brow + wr + m * 16 + r0 + r;
          float v = acc[m][n][r] + bv;
          if (EPI == 1) v = 0.5f * tanhf(v);
          ((_Float16*)Cout)[(size_t)row * N + col] = (_Float16)v;
        }
      }
    }
  } else {
    // =========================== PRODUCER (as r15) ===========================
    const int pw = wave - 4;            // 0..3
    const int prr = lane >> 3;          // 0..7 row within an 8-row issue
    const int pcol = ((lane & 7) ^ prr) * 8;  // T2 pre-swizzled source col
    const _Float16* Ab = A + (size_t)(brow + prr) * K + pcol;
    const _Float16* Bb = Bm + (size_t)(bcol + prr) * K + pcol;
    const int pdst = lane * 8;

    auto stageTo = [&](_Float16* pa, _Float16* pb, int t) {
#pragma unroll
      for (int i = 0; i < 8; i++) {
        const int r = pw * 64 + i * 8;  // A rows [pw*64, pw*64+64)
        GLD_LDS16(Ab + (size_t)r * K + t * 64, pa + r * 64 + pdst);
      }
#pragma unroll
      for (int i = 0; i < 4; i++) {
        const int r = pw * 32 + i * 8;  // B rows [pw*32, pw*32+32)
        GLD_LDS16(Bb + (size_t)r * K + t * 64, pb + r * 64 + pdst);
      }
    };

    stageTo(sa0, sb0, 0);
    stageTo(sa1, sb1, 1);
    asm volatile("s_waitcnt vmcnt(12)" ::: "memory");
    __builtin_amdgcn_s_barrier();
    MEMFENCE;

    for (int t = 0; t < nt; ++t) {
      if (t + 2 < nt) {
        stageTo(sa2, sb2, t + 2);
        asm volatile("s_waitcnt vmcnt(12)" ::: "memory");  // t+1 landed
      } else {
        asm volatile("s_waitcnt vmcnt(0)" ::: "memory");
      }
      __builtin_amdgcn_s_barrier();
      MEMFENCE;

      _Float16* ta = sa0; sa0 = sa1; sa1 = sa2; sa2 = ta;
      _Float16* tb = sb0; sb0 = sb1; sb1 = sb2; sb2 = tb;
    }
  }
}

// ---------------- r15 wave-specialized GEMM (8C+4P) for the head ------------
// EPI2 = acc+bias -> f32 ; NW=2 (BN=64).
__global__ __launch_bounds__(768, 3) void gemmws_head(
    const _Float16* __restrict__ A, const _Float16* __restrict__ Bm,
    const float* __restrict__ bias, float* __restrict__ Cout, int N, int K) {
  constexpr int NW = 2;
  constexpr int BN = 64;
  __shared__ _Float16 As[3][256 * 64];
  __shared__ _Float16 Bs[3][BN * 64];

  const int tid = threadIdx.x;
  const int lane = tid & 63;
  const int wave = tid >> 6;

  const int bid = blockIdx.x;
  const int xcd = bid & 7;
  const int idx = bid >> 3;
  const int brow = ((xcd >> 1) * 4 + (idx & 3)) * 256;
  const int bcol = ((xcd & 1) * 8 + (idx >> 2)) * BN;

  const int nt = K >> 6;

  _Float16* sa0 = As[0]; _Float16* sa1 = As[1]; _Float16* sa2 = As[2];
  _Float16* sb0 = Bs[0]; _Float16* sb1 = Bs[1]; _Float16* sb2 = Bs[2];

  if (wave < 8) {
    const int wr = (wave >> 1) * 64;
    const int wc = (wave & 1) * (BN / 2);

    const int frow = lane & 15;
    const int hi = lane >> 4;
    const int xr = lane & 7;

    int aoff[4], boff[NW];
#pragma unroll
    for (int m = 0; m < 4; m++) aoff[m] = (wr + m * 16 + frow) * 64;
#pragma unroll
    for (int n = 0; n < NW; n++) boff[n] = (wc + n * 16 + frow) * 64;
    const int ch0 = (hi ^ xr) * 8;
    const int ch1 = ((4 + hi) ^ xr) * 8;

    f32x4 acc[4][NW];
#pragma unroll
    for (int m = 0; m < 4; m++)
#pragma unroll
      for (int n = 0; n < NW; n++) acc[m][n] = f32x4{0.f, 0.f, 0.f, 0.f};

    __builtin_amdgcn_s_barrier();
    MEMFENCE;

    for (int t = 0; t < nt; ++t) {
      half8 a0[4], a1[4], b0[NW], b1[NW];
#pragma unroll
      for (int m = 0; m < 4; m++) a0[m] = *(const half8*)(sa0 + aoff[m] + ch0);
#pragma unroll
      for (int n = 0; n < NW; n++) b0[n] = *(const half8*)(sb0 + boff[n] + ch0);
#pragma unroll
      for (int m = 0; m < 4; m++) a1[m] = *(const half8*)(sa0 + aoff[m] + ch1);
#pragma unroll
      for (int n = 0; n < NW; n++) b1[n] = *(const half8*)(sb0 + boff[n] + ch1);

      __builtin_amdgcn_s_setprio(1);
#pragma unroll
      for (int m = 0; m < 4; m++)
#pragma unroll
        for (int n = 0; n < NW; n++)
          acc[m][n] = __builtin_amdgcn_mfma_f32_16x16x32_f16(a0[m], b0[n],
                                                             acc[m][n], 0, 0, 0);
#pragma unroll
      for (int m = 0; m < 4; m++)
#pragma unroll
        for (int n = 0; n < NW; n++)
          acc[m][n] = __builtin_amdgcn_mfma_f32_16x16x32_f16(a1[m], b1[n],
                                                             acc[m][n], 0, 0, 0);
      __builtin_amdgcn_s_setprio(0);

      asm volatile("s_waitcnt lgkmcnt(0)" ::: "memory");
      __builtin_amdgcn_s_barrier();
      MEMFENCE;

      _Float16* ta = sa0; sa0 = sa1; sa1 = sa2; sa2 = ta;
      _Float16* tb = sb0; sb0 = sb1; sb1 = sb2; sb2 = tb;
    }

    const int r0 = hi * 4;
    const int c0 = frow;
#pragma unroll
    for (int n = 0; n < NW; n++) {
      const int col = bcol + wc + n * 16 + c0;
      const float bv = bias[col];
#pragma unroll
      for (int m = 0; m < 4; m++) {
#pragma unroll
        for (int r = 0; r < 4; r++) {
          const int row = brow + wr + m * 16 + r0 + r;
          Cout[(size_t)row * N + col] = acc[m][n][r] + bv;
        }
      }
    }
  } else {
    const int pw = wave - 8;
    const int prr = lane >> 3;
    const int pcol = ((lane & 7) ^ prr) * 8;
    const _Float16* Ab = A + (size_t)(brow + prr) * K + pcol;
    const _Float16* Bb = Bm + (size_t)(bcol + prr) * K + pcol;
    const int pdst = lane * 8;
    constexpr int BI = BN / 32;     // 2
    constexpr int IPW = 8 + BI;     // 10

    auto stageTo = [&](_Float16* pa, _Float16* pb, int t) {
#pragma unroll
      for (int i = 0; i < 8; i++) {
        const int r = pw * 64 + i * 8;
        GLD_LDS16(Ab + (size_t)r * K + t * 64, pa + r * 64 + pdst);
      }
#pragma unroll
      for (int i = 0; i < BI; i++) {
        const int r = pw * (BN / 4) + i * 8;
        GLD_LDS16(Bb + (size_t)r * K + t * 64, pb + r * 64 + pdst);
      }
    };

    stageTo(sa0, sb0, 0);
    stageTo(sa1, sb1, 1);
    asm volatile("s_waitcnt vmcnt(%0)" ::"i"(IPW) : "memory");
    __builtin_amdgcn_s_barrier();
    MEMFENCE;

    for (int t = 0; t < nt; ++t) {
      if (t + 2 < nt) {
        stageTo(sa2, sb2, t + 2);
        asm volatile("s_waitcnt vmcnt(%0)" ::"i"(IPW) : "memory");
      } else {
        asm volatile("s_waitcnt vmcnt(0)" ::: "memory");
      }
      __builtin_amdgcn_s_barrier();
      MEMFENCE;

      _Float16* ta = sa0; sa0 = sa1; sa1 = sa2; sa2 = ta;
      _Float16* tb = sb0; sb0 = sb1; sb1 = sb2; sb2 = tb;
    }
  }
}

// ---------------------------------------------------------------------------
extern "C" void kernel_launch(void* const* d_in, const int* in_sizes, int n_in,
                              void* d_out, int out_size, void* d_ws,
                              size_t ws_size, hipStream_t stream) {
  (void)in_sizes;
  (void)n_in;
  (void)out_size;
  (void)ws_size;

  const float* x = (const float*)d_in[0];        // [4096,1024]
  const float* W_embed = (const float*)d_in[1];  // [2048,1024]
  const float* b_embed = (const float*)d_in[2];  // [2048]
  const float* W_layers = (const float*)d_in[3]; // [3,2048,2048]
  const float* b_layers = (const float*)d_in[4]; // [3,2048]
  const float* W_head = (const float*)d_in[5];   // [1024,2048]
  const float* b_head = (const float*)d_in[6];   // [1024]

  const int B = 4096, I = 1024, H = 2048, O = 1024;

  char* w = (char*)d_ws;
  auto carve = [&](size_t bytes) {
    char* p = w;
    w += (bytes + 255) & ~(size_t)255;
    return p;
  };
  _Float16* xh = (_Float16*)carve((size_t)B * I * 2);
  _Float16* Weh = (_Float16*)carve((size_t)H * I * 2);
  _Float16* Wlh = (_Float16*)carve((size_t)3 * H * H * 2);
  _Float16* Whh = (_Float16*)carve((size_t)O * H * 2);
  _Float16* bufE = (_Float16*)carve((size_t)B * H * 2);
  _Float16* bufA = (_Float16*)carve((size_t)B * H * 2);

  const long n0 = (long)B * I, n1 = (long)H * I, n2 = (long)3 * H * H,
             n3 = (long)O * H;
  const long nb0 = n0 / 2048, nb1 = n1 / 2048, nb2 = n2 / 2048,
             nb3 = n3 / 2048;
  cvt_all<<<(int)(nb0 + nb1 + nb2 + nb3), 256, 0, stream>>>(
      x, W_embed, W_layers, W_head, xh, Weh, Wlh, Whh, nb0, nb1, nb2);

  // all grids: 16x16 tiles = 256 blocks
  // x_emb = x @ W_embed^T + b_embed            [B,H], f16
  gemmw4<0><<<256, dim3(512), 0, stream>>>(xh, Weh, b_embed, bufE, H, I);
  // h0 = 0.5*tanh(x_emb @ W0^T + b0)           [B,H], f16
  gemmw4<1><<<256, dim3(512), 0, stream>>>(bufE, Wlh, b_layers, bufA, H, H);
  // h1 = 0.5*tanh(h0 @ W1^T + b1)              [B,H], f16
  gemmw4<1><<<256, dim3(512), 0, stream>>>(bufA, Wlh + (size_t)H * H,
                                           b_layers + H, bufE, H, H);
  // h2 = 0.5*tanh(h1 @ W2^T + b2)              [B,H], f16
  gemmw4<1><<<256, dim3(512), 0, stream>>>(bufE, Wlh + (size_t)2 * H * H,
                                           b_layers + 2 * H, bufA, H, H);
  // out = h2 @ W_head^T + b_head               [B,O], f32
  gemmws_head<<<256, dim3(768), 0, stream>>>(bufA, Whh, b_head, (float*)d_out,
                                             O, H);
}